// Round 2
// baseline (5372.165 us; speedup 1.0000x reference)
//
#include <hip/hip_runtime.h>

#define NUSERS 100000
#define NITEMS 200000
#define EMBED  64
#define NTOT   300000
#define NNZE   2000000

// ---------------------------------------------------------------------------
// init: x0 = concat(user_emb, item_emb); acc = x0   (all float4-vectorized)
// ---------------------------------------------------------------------------
__global__ void init_kernel(const float4* __restrict__ user,
                            const float4* __restrict__ item,
                            float4* __restrict__ xprev,
                            float4* __restrict__ acc) {
    const long total = (long)NTOT * EMBED / 4;          // 4.8M float4
    const long ubound = (long)NUSERS * EMBED / 4;
    for (long i = blockIdx.x * (long)blockDim.x + threadIdx.x; i < total;
         i += (long)gridDim.x * blockDim.x) {
        float4 v = (i < ubound) ? user[i] : item[i - ubound];
        xprev[i] = v;
        acc[i]   = v;
    }
}

// ---------------------------------------------------------------------------
// COO SpMM: y[row[e]] += vals[e] * x[col[e]]  (y must be pre-zeroed)
// 16 threads per edge, one float4 quad each -> 256B coalesced gather/scatter.
// ---------------------------------------------------------------------------
__global__ void spmm_kernel(const float* __restrict__ vals,
                            const int*   __restrict__ row,
                            const int*   __restrict__ col,
                            const float* __restrict__ x,
                            float*       __restrict__ y) {
    const long total = (long)NNZE * 16;
    for (long t = blockIdx.x * (long)blockDim.x + threadIdx.x; t < total;
         t += (long)gridDim.x * blockDim.x) {
        const int e = (int)(t >> 4);
        const int q = (int)(t & 15);
        const float v = vals[e];
        const int   r = row[e];
        const int   c = col[e];
        const float4 xv = *reinterpret_cast<const float4*>(x + (long)c * EMBED + q * 4);
        float* yp = y + (long)r * EMBED + q * 4;
        atomicAdd(yp + 0, v * xv.x);
        atomicAdd(yp + 1, v * xv.y);
        atomicAdd(yp + 2, v * xv.z);
        atomicAdd(yp + 3, v * xv.w);
    }
}

// ---------------------------------------------------------------------------
// acc += x
// ---------------------------------------------------------------------------
__global__ void add_kernel(float4* __restrict__ acc, const float4* __restrict__ x) {
    const long total = (long)NTOT * EMBED / 4;
    for (long i = blockIdx.x * (long)blockDim.x + threadIdx.x; i < total;
         i += (long)gridDim.x * blockDim.x) {
        float4 a = acc[i];
        float4 b = x[i];
        a.x += b.x; a.y += b.y; a.z += b.z; a.w += b.w;
        acc[i] = a;
    }
}

// ---------------------------------------------------------------------------
// out = (acc + x) * 0.25   (final layer add fused with the /(N_LAYERS+1) scale)
// ---------------------------------------------------------------------------
__global__ void final_kernel(float4* __restrict__ acc, const float4* __restrict__ x) {
    const long total = (long)NTOT * EMBED / 4;
    for (long i = blockIdx.x * (long)blockDim.x + threadIdx.x; i < total;
         i += (long)gridDim.x * blockDim.x) {
        float4 a = acc[i];
        float4 b = x[i];
        a.x = (a.x + b.x) * 0.25f;
        a.y = (a.y + b.y) * 0.25f;
        a.z = (a.z + b.z) * 0.25f;
        a.w = (a.w + b.w) * 0.25f;
        acc[i] = a;
    }
}

extern "C" void kernel_launch(void* const* d_in, const int* in_sizes, int n_in,
                              void* d_out, int out_size, void* d_ws, size_t ws_size,
                              hipStream_t stream) {
    const float* user = (const float*)d_in[0];
    const float* item = (const float*)d_in[1];
    const float* vals = (const float*)d_in[2];
    const int*   row  = (const int*)d_in[3];
    const int*   col  = (const int*)d_in[4];

    float* acc = (float*)d_out;                     // accumulator lives in d_out
    float* x0  = (float*)d_ws;                      // ping
    float* x1  = x0 + (size_t)NTOT * EMBED;         // pong
    const size_t xbytes = (size_t)NTOT * EMBED * sizeof(float);   // 76.8 MB

    const dim3 eb(256), eg(2048);                   // elementwise: grid-stride
    const dim3 sb(256), sg(4096);                   // spmm: grid-stride over 32M units

    init_kernel<<<eg, eb, 0, stream>>>((const float4*)user, (const float4*)item,
                                       (float4*)x0, (float4*)acc);

    // layer 1: x1 = A*x0 ; acc += x1
    hipMemsetAsync(x1, 0, xbytes, stream);
    spmm_kernel<<<sg, sb, 0, stream>>>(vals, row, col, x0, x1);
    add_kernel<<<eg, eb, 0, stream>>>((float4*)acc, (const float4*)x1);

    // layer 2: x0 = A*x1 ; acc += x0
    hipMemsetAsync(x0, 0, xbytes, stream);
    spmm_kernel<<<sg, sb, 0, stream>>>(vals, row, col, x1, x0);
    add_kernel<<<eg, eb, 0, stream>>>((float4*)acc, (const float4*)x0);

    // layer 3: x1 = A*x0 ; out = (acc + x1) * 0.25
    hipMemsetAsync(x1, 0, xbytes, stream);
    spmm_kernel<<<sg, sb, 0, stream>>>(vals, row, col, x0, x1);
    final_kernel<<<eg, eb, 0, stream>>>((float4*)acc, (const float4*)x1);
}

// Round 3
// 706.513 us; speedup vs baseline: 7.6038x; 7.6038x over previous
//
#include <hip/hip_runtime.h>

#define NUSERS 100000
#define NITEMS 200000
#define EMBED  64
#define NTOT   300000
#define NNZE   2000000
#define NB_SCAN ((NTOT + 255) / 256)   // 1172 chunks of 256

// ---------------------------------------------------------------------------
// init: x0 = concat(user_emb, item_emb); acc = x0   (float4-vectorized)
// ---------------------------------------------------------------------------
__global__ void init_kernel(const float4* __restrict__ user,
                            const float4* __restrict__ item,
                            float4* __restrict__ x0,
                            float4* __restrict__ acc) {
    const long total  = (long)NTOT * EMBED / 4;
    const long ubound = (long)NUSERS * EMBED / 4;
    for (long i = blockIdx.x * (long)blockDim.x + threadIdx.x; i < total;
         i += (long)gridDim.x * blockDim.x) {
        float4 v = (i < ubound) ? user[i] : item[i - ubound];
        x0[i]  = v;
        acc[i] = v;
    }
}

// ---------------------------------------------------------------------------
// CSR build step 1: row histogram (counts must be pre-zeroed)
// ---------------------------------------------------------------------------
__global__ void hist_kernel(const int* __restrict__ row, int* __restrict__ counts) {
    int e = blockIdx.x * blockDim.x + threadIdx.x;
    if (e < NNZE) atomicAdd(&counts[row[e]], 1);
}

// ---------------------------------------------------------------------------
// CSR build step 2: per-256-chunk sums
// ---------------------------------------------------------------------------
__global__ void chunk_reduce_kernel(const int* __restrict__ counts, int* __restrict__ sums) {
    __shared__ int s[256];
    const int t = threadIdx.x;
    const int i = blockIdx.x * 256 + t;
    int v = (i < NTOT) ? counts[i] : 0;
    s[t] = v;
    __syncthreads();
    for (int off = 128; off > 0; off >>= 1) {
        if (t < off) s[t] += s[t + off];
        __syncthreads();
    }
    if (t == 0) sums[blockIdx.x] = s[0];
}

// ---------------------------------------------------------------------------
// CSR build step 3: single-block exclusive scan of chunk sums (NB_SCAN elems)
// ---------------------------------------------------------------------------
__global__ void scan_sums_kernel(int* __restrict__ sums) {
    __shared__ int s[256];
    const int t = threadIdx.x;
    int carry = 0;
    for (int base = 0; base < NB_SCAN; base += 256) {
        const int i = base + t;
        int v = (i < NB_SCAN) ? sums[i] : 0;
        s[t] = v;
        __syncthreads();
        // Hillis-Steele inclusive scan
        for (int off = 1; off < 256; off <<= 1) {
            int tmp = (t >= off) ? s[t - off] : 0;
            __syncthreads();
            s[t] += tmp;
            __syncthreads();
        }
        const int incl  = s[t];
        const int total = s[255];
        if (i < NB_SCAN) sums[i] = carry + incl - v;   // exclusive
        carry += total;
        __syncthreads();
    }
}

// ---------------------------------------------------------------------------
// CSR build step 4: per-chunk exclusive scan + chunk offset -> row_ptr, next
// ---------------------------------------------------------------------------
__global__ void finalize_scan_kernel(const int* __restrict__ counts,
                                     const int* __restrict__ sums,
                                     int* __restrict__ row_ptr,
                                     int* __restrict__ next) {
    __shared__ int s[256];
    const int t = threadIdx.x;
    const int i = blockIdx.x * 256 + t;
    int v = (i < NTOT) ? counts[i] : 0;
    s[t] = v;
    __syncthreads();
    for (int off = 1; off < 256; off <<= 1) {
        int tmp = (t >= off) ? s[t - off] : 0;
        __syncthreads();
        s[t] += tmp;
        __syncthreads();
    }
    if (i < NTOT) {
        const int rp = sums[blockIdx.x] + s[t] - v;   // exclusive
        row_ptr[i] = rp;
        next[i]    = rp;
    }
    if (i == 0) row_ptr[NTOT] = NNZE;
}

// ---------------------------------------------------------------------------
// CSR build step 5: scatter edges into permuted (ecol, eval) lists
// ---------------------------------------------------------------------------
__global__ void scatter_kernel(const float* __restrict__ vals,
                               const int*   __restrict__ row,
                               const int*   __restrict__ col,
                               int*   __restrict__ next,
                               int*   __restrict__ ecol,
                               float* __restrict__ eval) {
    int e = blockIdx.x * blockDim.x + threadIdx.x;
    if (e < NNZE) {
        const int pos = atomicAdd(&next[row[e]], 1);
        ecol[pos] = col[e];
        eval[pos] = vals[e];
    }
}

// ---------------------------------------------------------------------------
// Gather-side SpMM, no atomics. 16 threads per row (one float4 quad each).
// MODE 0: y[r] = sum; acc[r] += sum          (intermediate layers)
// MODE 1: acc[r] = (acc[r] + sum) * 0.25     (final layer; y not written)
// ---------------------------------------------------------------------------
template <int MODE>
__global__ void spmm_csr_kernel(const int*   __restrict__ row_ptr,
                                const int*   __restrict__ ecol,
                                const float* __restrict__ eval,
                                const float* __restrict__ x,
                                float*       __restrict__ y,
                                float*       __restrict__ acc) {
    const long t = blockIdx.x * (long)blockDim.x + threadIdx.x;
    if (t >= (long)NTOT * 16) return;
    const int r = (int)(t >> 4);
    const int q = (int)(t & 15);

    const int start = row_ptr[r];
    const int end   = row_ptr[r + 1];

    float4 a = make_float4(0.f, 0.f, 0.f, 0.f);
    for (int j = start; j < end; ++j) {
        const int   c = ecol[j];
        const float v = eval[j];
        const float4 xv = *reinterpret_cast<const float4*>(x + (long)c * EMBED + q * 4);
        a.x += v * xv.x;
        a.y += v * xv.y;
        a.z += v * xv.z;
        a.w += v * xv.w;
    }

    const long o = (long)r * EMBED + q * 4;
    float4* accp = reinterpret_cast<float4*>(acc + o);
    float4  old  = *accp;
    if (MODE == 0) {
        *reinterpret_cast<float4*>(y + o) = a;
        old.x += a.x; old.y += a.y; old.z += a.z; old.w += a.w;
        *accp = old;
    } else {
        old.x = (old.x + a.x) * 0.25f;
        old.y = (old.y + a.y) * 0.25f;
        old.z = (old.z + a.z) * 0.25f;
        old.w = (old.w + a.w) * 0.25f;
        *accp = old;
    }
}

extern "C" void kernel_launch(void* const* d_in, const int* in_sizes, int n_in,
                              void* d_out, int out_size, void* d_ws, size_t ws_size,
                              hipStream_t stream) {
    const float* user = (const float*)d_in[0];
    const float* item = (const float*)d_in[1];
    const float* vals = (const float*)d_in[2];
    const int*   row  = (const int*)d_in[3];
    const int*   col  = (const int*)d_in[4];

    float* acc = (float*)d_out;

    // workspace layout
    char* w = (char*)d_ws;
    float* x0      = (float*)w;                 w += (size_t)NTOT * EMBED * 4;   // 76.8 MB
    float* x1      = (float*)w;                 w += (size_t)NTOT * EMBED * 4;   // 76.8 MB
    float* eval    = (float*)w;                 w += (size_t)NNZE * 4;           // 8 MB
    int*   ecol    = (int*)w;                   w += (size_t)NNZE * 4;           // 8 MB
    int*   counts  = (int*)w;                   w += (size_t)NTOT * 4;           // 1.2 MB
    int*   next    = (int*)w;                   w += (size_t)NTOT * 4;           // 1.2 MB
    int*   row_ptr = (int*)w;                   w += (size_t)(NTOT + 1) * 4;     // 1.2 MB
    int*   sums    = (int*)w;                   w += (size_t)NB_SCAN * 4;

    const int EDGE_BLOCKS = (NNZE + 255) / 256;          // 7813
    const int SPMM_BLOCKS = (int)(((long)NTOT * 16 + 255) / 256);  // 18750
    const dim3 eb(256), eg(2048);

    // ---- build CSR (once; reused by all 3 layers) ----
    hipMemsetAsync(counts, 0, (size_t)NTOT * 4, stream);
    hist_kernel<<<EDGE_BLOCKS, 256, 0, stream>>>(row, counts);
    chunk_reduce_kernel<<<NB_SCAN, 256, 0, stream>>>(counts, sums);
    scan_sums_kernel<<<1, 256, 0, stream>>>(sums);
    finalize_scan_kernel<<<NB_SCAN, 256, 0, stream>>>(counts, sums, row_ptr, next);
    scatter_kernel<<<EDGE_BLOCKS, 256, 0, stream>>>(vals, row, col, next, ecol, eval);

    // ---- init ego / acc ----
    init_kernel<<<eg, eb, 0, stream>>>((const float4*)user, (const float4*)item,
                                       (float4*)x0, (float4*)acc);

    // ---- 3 propagation layers, acc-add fused ----
    spmm_csr_kernel<0><<<SPMM_BLOCKS, 256, 0, stream>>>(row_ptr, ecol, eval, x0, x1, acc);
    spmm_csr_kernel<0><<<SPMM_BLOCKS, 256, 0, stream>>>(row_ptr, ecol, eval, x1, x0, acc);
    spmm_csr_kernel<1><<<SPMM_BLOCKS, 256, 0, stream>>>(row_ptr, ecol, eval, x0, x1, acc);
}

// Round 4
// 688.208 us; speedup vs baseline: 7.8060x; 1.0266x over previous
//
#include <hip/hip_runtime.h>

#define NUSERS 100000
#define NITEMS 200000
#define EMBED  64
#define NTOT   300000
#define NNZE   2000000
#define NB_SCAN ((NTOT + 255) / 256)   // 1172 chunks of 256

typedef unsigned long long u64;
typedef unsigned int       u32;

// ---------------------------------------------------------------------------
// CSR build step 1: row histogram (counts must be pre-zeroed)
// ---------------------------------------------------------------------------
__global__ void hist_kernel(const int* __restrict__ row, int* __restrict__ counts) {
    int e = blockIdx.x * blockDim.x + threadIdx.x;
    if (e < NNZE) atomicAdd(&counts[row[e]], 1);
}

// ---------------------------------------------------------------------------
// CSR build step 2: per-256-chunk sums
// ---------------------------------------------------------------------------
__global__ void chunk_reduce_kernel(const int* __restrict__ counts, int* __restrict__ sums) {
    __shared__ int s[256];
    const int t = threadIdx.x;
    const int i = blockIdx.x * 256 + t;
    int v = (i < NTOT) ? counts[i] : 0;
    s[t] = v;
    __syncthreads();
    for (int off = 128; off > 0; off >>= 1) {
        if (t < off) s[t] += s[t + off];
        __syncthreads();
    }
    if (t == 0) sums[blockIdx.x] = s[0];
}

// ---------------------------------------------------------------------------
// CSR build step 3: single-block exclusive scan of chunk sums
// ---------------------------------------------------------------------------
__global__ void scan_sums_kernel(int* __restrict__ sums) {
    __shared__ int s[256];
    const int t = threadIdx.x;
    int carry = 0;
    for (int base = 0; base < NB_SCAN; base += 256) {
        const int i = base + t;
        int v = (i < NB_SCAN) ? sums[i] : 0;
        s[t] = v;
        __syncthreads();
        for (int off = 1; off < 256; off <<= 1) {
            int tmp = (t >= off) ? s[t - off] : 0;
            __syncthreads();
            s[t] += tmp;
            __syncthreads();
        }
        const int incl  = s[t];
        const int total = s[255];
        if (i < NB_SCAN) sums[i] = carry + incl - v;   // exclusive
        carry += total;
        __syncthreads();
    }
}

// ---------------------------------------------------------------------------
// CSR build step 4: per-chunk exclusive scan + chunk offset -> row_ptr, next
// ---------------------------------------------------------------------------
__global__ void finalize_scan_kernel(const int* __restrict__ counts,
                                     const int* __restrict__ sums,
                                     int* __restrict__ row_ptr,
                                     int* __restrict__ next) {
    __shared__ int s[256];
    const int t = threadIdx.x;
    const int i = blockIdx.x * 256 + t;
    int v = (i < NTOT) ? counts[i] : 0;
    s[t] = v;
    __syncthreads();
    for (int off = 1; off < 256; off <<= 1) {
        int tmp = (t >= off) ? s[t - off] : 0;
        __syncthreads();
        s[t] += tmp;
        __syncthreads();
    }
    if (i < NTOT) {
        const int rp = sums[blockIdx.x] + s[t] - v;   // exclusive
        row_ptr[i] = rp;
        next[i]    = rp;
    }
    if (i == 0) row_ptr[NTOT] = NNZE;
}

// ---------------------------------------------------------------------------
// CSR build step 5: scatter edges as PACKED 8-byte words (col<<32 | val bits)
// -> one random store per edge instead of two (halves dirty-line traffic)
// ---------------------------------------------------------------------------
__global__ void scatter_kernel(const float* __restrict__ vals,
                               const int*   __restrict__ row,
                               const int*   __restrict__ col,
                               int*  __restrict__ next,
                               u64*  __restrict__ edges) {
    int e = blockIdx.x * blockDim.x + threadIdx.x;
    if (e < NNZE) {
        const int pos = atomicAdd(&next[row[e]], 1);
        const u64 w = ((u64)(u32)col[e] << 32) | (u64)__float_as_uint(vals[e]);
        edges[pos] = w;
    }
}

// ---------------------------------------------------------------------------
// Gather-side SpMM, no atomics. 16 threads per row (one float4 quad each).
// MODE 0 (layer 1, init fused): gather from user/item; y=sum; acc = ego(r)+sum
// MODE 1 (layer 2):            gather from x;        y=sum; acc += sum
// MODE 2 (layer 3, final):     gather from x;        acc = (acc+sum)*0.25
// ---------------------------------------------------------------------------
__device__ __forceinline__ const float* ego_ptr(const float* __restrict__ user,
                                                const float* __restrict__ item,
                                                int c) {
    return (c < NUSERS) ? (user + (long)c * EMBED)
                        : (item + (long)(c - NUSERS) * EMBED);
}

template <int MODE>
__global__ void spmm_csr_kernel(const int* __restrict__ row_ptr,
                                const u64* __restrict__ edges,
                                const float* __restrict__ x,     // MODE 1,2
                                const float* __restrict__ user,  // MODE 0
                                const float* __restrict__ item,  // MODE 0
                                float* __restrict__ y,           // MODE 0,1
                                float* __restrict__ acc) {
    const long t = blockIdx.x * (long)blockDim.x + threadIdx.x;
    if (t >= (long)NTOT * 16) return;
    const int r = (int)(t >> 4);
    const int q = (int)(t & 15);

    const int start = row_ptr[r];
    const int end   = row_ptr[r + 1];

    float4 a = make_float4(0.f, 0.f, 0.f, 0.f);
    for (int j = start; j < end; ++j) {
        const u64 w = edges[j];
        const int   c = (int)(w >> 32);
        const float v = __uint_as_float((u32)w);
        const float* xp = (MODE == 0) ? ego_ptr(user, item, c)
                                      : (x + (long)c * EMBED);
        const float4 xv = *reinterpret_cast<const float4*>(xp + q * 4);
        a.x += v * xv.x;
        a.y += v * xv.y;
        a.z += v * xv.z;
        a.w += v * xv.w;
    }

    const long o = (long)r * EMBED + q * 4;
    if (MODE == 0) {
        *reinterpret_cast<float4*>(y + o) = a;
        const float4 ego = *reinterpret_cast<const float4*>(ego_ptr(user, item, r) + q * 4);
        a.x += ego.x; a.y += ego.y; a.z += ego.z; a.w += ego.w;
        *reinterpret_cast<float4*>(acc + o) = a;
    } else if (MODE == 1) {
        *reinterpret_cast<float4*>(y + o) = a;
        float4 old = *reinterpret_cast<float4*>(acc + o);
        old.x += a.x; old.y += a.y; old.z += a.z; old.w += a.w;
        *reinterpret_cast<float4*>(acc + o) = old;
    } else {
        float4 old = *reinterpret_cast<float4*>(acc + o);
        old.x = (old.x + a.x) * 0.25f;
        old.y = (old.y + a.y) * 0.25f;
        old.z = (old.z + a.z) * 0.25f;
        old.w = (old.w + a.w) * 0.25f;
        *reinterpret_cast<float4*>(acc + o) = old;
    }
}

extern "C" void kernel_launch(void* const* d_in, const int* in_sizes, int n_in,
                              void* d_out, int out_size, void* d_ws, size_t ws_size,
                              hipStream_t stream) {
    const float* user = (const float*)d_in[0];
    const float* item = (const float*)d_in[1];
    const float* vals = (const float*)d_in[2];
    const int*   row  = (const int*)d_in[3];
    const int*   col  = (const int*)d_in[4];

    float* acc = (float*)d_out;

    // workspace layout
    char* w = (char*)d_ws;
    float* x1      = (float*)w;  w += (size_t)NTOT * EMBED * 4;     // 76.8 MB
    float* x2      = (float*)w;  w += (size_t)NTOT * EMBED * 4;     // 76.8 MB
    u64*   edges   = (u64*)w;    w += (size_t)NNZE * 8;             // 16 MB
    int*   counts  = (int*)w;    w += (size_t)NTOT * 4;
    int*   next    = (int*)w;    w += (size_t)NTOT * 4;
    int*   row_ptr = (int*)w;    w += (size_t)(NTOT + 1) * 4;
    int*   sums    = (int*)w;    w += (size_t)NB_SCAN * 4;

    const int EDGE_BLOCKS = (NNZE + 255) / 256;                      // 7813
    const int SPMM_BLOCKS = (int)(((long)NTOT * 16 + 255) / 256);    // 18750

    // ---- build CSR (once; reused by all 3 layers) ----
    hipMemsetAsync(counts, 0, (size_t)NTOT * 4, stream);
    hist_kernel<<<EDGE_BLOCKS, 256, 0, stream>>>(row, counts);
    chunk_reduce_kernel<<<NB_SCAN, 256, 0, stream>>>(counts, sums);
    scan_sums_kernel<<<1, 256, 0, stream>>>(sums);
    finalize_scan_kernel<<<NB_SCAN, 256, 0, stream>>>(counts, sums, row_ptr, next);
    scatter_kernel<<<EDGE_BLOCKS, 256, 0, stream>>>(vals, row, col, next, edges);

    // ---- 3 propagation layers (init fused into layer 1, scale into layer 3) ----
    spmm_csr_kernel<0><<<SPMM_BLOCKS, 256, 0, stream>>>(row_ptr, edges, nullptr, user, item, x1, acc);
    spmm_csr_kernel<1><<<SPMM_BLOCKS, 256, 0, stream>>>(row_ptr, edges, x1, nullptr, nullptr, x2, acc);
    spmm_csr_kernel<2><<<SPMM_BLOCKS, 256, 0, stream>>>(row_ptr, edges, x2, nullptr, nullptr, nullptr, acc);
}